// Round 11
// baseline (133.755 us; speedup 1.0000x reference)
//
#include <hip/hip_runtime.h>
#include <math.h>

// ---------------- problem constants ----------------
#define NB 8          // batch
#define NM 16         // modes
#define NPH 8         // photons
#define NSTATES 12870 // C(16,8)
#define NSUB 256      // 2^NPH column subsets
#define OUTS 128
#define NTILES 824    // sum over classes of ceil(R/4)*ceil(C/4)
#define NSLOTS (NTILES*16) // 13184
#define NSG 16        // s-groups of 16
#define SPH 16        // s per producer block
#define NTG 4         // tile groups
#define TILES_PER_TG 206
#define NGRID 512     // NB * NSG * NTG
#define SLOTS_P2 16
#define NP2 824       // one tile per block; 824*16 == NSLOTS

// ---------------- compile-time tables ----------------
struct Tables {
  int binom[17][9];
  unsigned char cls_masks[256];
  int cls_off[10];
  int nt1[9], nt2[9];
  int tile_off[10];
};

constexpr int cpopc(int x){ int c=0; while(x){ c += x & 1; x >>= 1; } return c; }

constexpr Tables make_tables(){
  Tables t{};
  for (int n=0;n<=16;n++)
    for (int k=0;k<=8;k++){
      if (k==0) t.binom[n][k]=1;
      else if (n==0) t.binom[n][k]=0;
      else t.binom[n][k]=t.binom[n-1][k-1]+t.binom[n-1][k];
    }
  int idx=0;
  for (int p=0;p<=8;p++){
    t.cls_off[p]=idx;
    for (int m=0;m<256;m++) if (cpopc(m)==p) t.cls_masks[idx++]=(unsigned char)m;
  }
  t.cls_off[9]=idx; // 256
  int toff=0;
  for (int c=0;c<=8;c++){
    int R=t.binom[8][c], C=t.binom[8][8-c];
    t.nt1[c]=(R+3)/4; t.nt2[c]=(C+3)/4;
    t.tile_off[c]=toff; toff += t.nt1[c]*t.nt2[c];
  }
  t.tile_off[9]=toff;
  return t;
}

constexpr Tables HTBL = make_tables();
static_assert(HTBL.tile_off[9]==NTILES, "tile count");
static_assert(HTBL.cls_off[9]==256, "mask count");
__device__ const Tables TBL = HTBL;

// ---------------- workspace layout (bytes) ----------------
#define WS_TMAP   256               // NSLOTS ints = 52736 -> 52992 (pads never read)
#define WS_BSUM2  53248             // [NP2][NB] float = 26368 -> 79616
#define WS_POUT2  79872             // [NP2][NB*OUTS] float = 3375104 -> 3454976
#define WS_PART   3455232           // [NB][NSG][NSLOTS] float2 = 13500416

// ---------------- complex helpers ----------------
__device__ __forceinline__ float2 cmul(float2 a, float2 b){
  return make_float2(fmaf(a.x,b.x,-(a.y*b.y)), fmaf(a.x,b.y, a.y*b.x));
}
__device__ __forceinline__ void cmac(float2& acc, float2 a, float2 b){
  acc.x = fmaf(a.x, b.x, acc.x); acc.x = fmaf(-a.y, b.y, acc.x);
  acc.y = fmaf(a.x, b.y, acc.y); acc.y = fmaf(a.y, b.x, acc.y);
}

// ============ K1: fused setup + barrier-light Ryser main (R8-verified) =====
// grid 512 = NB(8) x NSG(16) x NTG(4); 64 KB LDS, 256 thr -> 2 blocks/CU.
__global__ __launch_bounds__(256) void k_p1(
    const float* __restrict__ x, const float* __restrict__ th1,
    const float* __restrict__ th2, const float* __restrict__ mr,
    const float* __restrict__ mi, const int* __restrict__ rows, char* ws)
{
  __shared__ float2 P[32][256];      // 64 KB; row ts = table*16+s, col swizzled
  float2* __restrict__ part = (float2*)(ws + WS_PART);
  int tid = threadIdx.x;
  int blk = blockIdx.x;
  int b = blk >> 6, rest = blk & 63, sg = rest >> 2, tg = rest & 3;
  int sbase = sg * SPH;

  // prologue scratch aliased over P (dead before fill)
  float2 (*T1)[NM]  = reinterpret_cast<float2(*)[NM]>(P[0]);
  float2 (*T2)[NM]  = reinterpret_cast<float2(*)[NM]>(P[1]);
  float2 (*Am)[NM]  = reinterpret_cast<float2(*)[NM]>(P[2]);
  float2 (*Bm)[NM]  = reinterpret_cast<float2(*)[NM]>(P[3]);
  float2 (*EA)[NPH] = reinterpret_cast<float2(*)[NPH]>(P[4]);
  float2* exP = P[4] + 128;
  float2 (*UinL)[NPH] = reinterpret_cast<float2(*)[NPH]>(P[5]);

  {
    int r = tid >> 4, cc = tid & 15;
    float sn, cs;
    sincosf(th1[r], &sn, &cs);
    float a = mr[0*256 + tid], bb = mi[0*256 + tid];
    T1[r][cc] = make_float2(cs*a - sn*bb, cs*bb + sn*a);
    sincosf(th2[r], &sn, &cs);
    float a2 = mr[2*256 + tid], b2 = mi[2*256 + tid];
    T2[r][cc] = make_float2(cs*a2 - sn*b2, cs*b2 + sn*a2);
    if (tid < NM){ float s2, c2; sincosf(x[b*NM + tid], &s2, &c2); exP[tid] = make_float2(c2, s2); }
  }
  __syncthreads();
  {
    int r = tid >> 4, cc = tid & 15;
    float2 accA = make_float2(0,0), accB = make_float2(0,0);
    for (int m=0;m<NM;m++){
      float2 m1 = make_float2(mr[1*256 + r*16+m], mi[1*256 + r*16+m]);
      cmac(accA, m1, T1[m][cc]);
      float2 m3 = make_float2(mr[3*256 + r*16+m], mi[3*256 + r*16+m]);
      cmac(accB, m3, T2[m][cc]);
    }
    Am[r][cc] = accA; Bm[r][cc] = accB;
  }
  __syncthreads();
  if (tid < NM*NPH){ int m = tid >> 3, n = tid & 7; EA[m][n] = cmul(exP[m], Am[m][n]); }
  __syncthreads();
  if (tid < NM*NPH){
    int p = tid >> 3, n = tid & 7;
    float2 acc = make_float2(0,0);
    for (int m=0;m<NM;m++) cmac(acc, Bm[p][m], EA[m][n]);
    UinL[p][n] = acc;
  }
  __syncthreads();

  // per-thread V extraction into registers (same sum order as original)
  int ts = tid >> 3;
  int table = ts >> 4, sl = ts & 15;
  int sv = sbase + sl;
  float2 v[8];
  {
    #pragma unroll
    for (int j=0;j<8;j++){
      float2 a = make_float2(0,0);
      int m = table*8 + j;
      #pragma unroll
      for (int jj=0;jj<NPH;jj++)
        if ((sv>>jj) & 1){ a.x += UinL[m][jj].x; a.y += UinL[m][jj].y; }
      v[j] = a;
    }
  }
  __syncthreads();   // prologue scratch dead

  // fill: register DP in two 16-value halves (bit-identical multiply tree)
  {
    int chunk = tid & 7;
    int t0 = chunk << 5;
    int swz = (ts & 15) << 1;
    float2 ph = make_float2((table==0 && (__popc(sv)&1)) ? -1.0f : 1.0f, 0.0f);
    if (chunk & 4) ph = cmul(ph, v[7]);
    if (chunk & 2) ph = cmul(ph, v[6]);
    if (chunk & 1) ph = cmul(ph, v[5]);

    float2 pl[16];
    // half A: u = 0..15, root ph
    pl[0] = ph;
    #pragma unroll
    for (int w=1; w<16; w++){
      int par = w & (w-1);
      int lb = (w&1) ? 0 : ((w&2) ? 1 : ((w&4) ? 2 : 3));
      pl[w] = cmul(pl[par], v[lb]);
    }
    #pragma unroll
    for (int w=0; w<16; w+=2){
      int tc = (t0 + w) ^ swz;
      *(float4*)&P[ts][tc] = make_float4(pl[w].x, pl[w].y, pl[w+1].x, pl[w+1].y);
    }
    // half B: u = 16..31, root ph*v[4]  (== original p[16])
    pl[0] = cmul(ph, v[4]);
    #pragma unroll
    for (int w=1; w<16; w++){
      int par = w & (w-1);
      int lb = (w&1) ? 0 : ((w&2) ? 1 : ((w&4) ? 2 : 3));
      pl[w] = cmul(pl[par], v[lb]);
    }
    #pragma unroll
    for (int w=0; w<16; w+=2){
      int tc = (t0 + 16 + w) ^ swz;
      *(float4*)&P[ts][tc] = make_float4(pl[w].x, pl[w].y, pl[w+1].x, pl[w+1].y);
    }
  }

  // combine-thread tile masks
  bool active = tid < TILES_PER_TG;
  int tile = tg + 4*tid;
  int t1v[4] = {0,0,0,0}, t2v[4] = {0,0,0,0};
  if (active){
    int c = 0;
    while (tile >= TBL.tile_off[c+1]) c++;
    int local = tile - TBL.tile_off[c];
    int n2 = TBL.nt2[c];
    int ti = local / n2, tj = local - ti*n2;
    int R = TBL.binom[8][c], C2 = TBL.binom[8][8-c];
    #pragma unroll
    for (int i=0;i<4;i++){ int r1 = ti*4+i; t1v[i] = (r1<R) ? (int)TBL.cls_masks[TBL.cls_off[c]+r1] : 0; }
    #pragma unroll
    for (int j=0;j<4;j++){ int r2 = tj*4+j; t2v[j] = (r2<C2) ? (int)TBL.cls_masks[TBL.cls_off[8-c]+r2] : 0; }
  }
  __syncthreads();   // P table ready

  if (active){
    float2 acc[4][4] = {};
    for (int s=0;s<SPH;s++){
      int swz = s << 1;
      float2 av[4], bv[4];
      #pragma unroll
      for (int i=0;i<4;i++) av[i] = P[s][t1v[i] ^ swz];
      #pragma unroll
      for (int j=0;j<4;j++) bv[j] = P[16+s][t2v[j] ^ swz];
      #pragma unroll
      for (int i=0;i<4;i++)
        #pragma unroll
        for (int j=0;j<4;j++) cmac(acc[i][j], av[i], bv[j]);
    }
    float2* dst = part + (size_t)(b*NSG + sg)*NSLOTS + (size_t)tile*16;
    #pragma unroll
    for (int i=0;i<4;i++)
      #pragma unroll
      for (int j=0;j<4;j++) dst[i*4+j] = acc[i][j];
  }

  // tile map: tg==3 blocks rank 101 states each
  if (tg == 3){
    int idx = blk >> 2;
    int kb = idx * 101;
    int ke = min(NSTATES, kb + 101);
    int k = kb + tid;
    if (k < ke){
      int t1=0, t2=0;
      #pragma unroll
      for (int i=0;i<NPH;i++){
        int rr = rows[k*NPH+i];
        if (rr < 8) t1 |= 1 << rr; else t2 |= 1 << (rr-8);
      }
      int c1 = __popc(t1);
      int rk1=0, cnt=0;
      #pragma unroll
      for (int bb=0;bb<8;bb++) if ((t1>>bb)&1){ cnt++; rk1 += TBL.binom[bb][cnt]; }
      int rk2=0; cnt=0;
      #pragma unroll
      for (int bb=0;bb<8;bb++) if ((t2>>bb)&1){ cnt++; rk2 += TBL.binom[bb][cnt]; }
      int tl = TBL.tile_off[c1] + (rk1>>2)*TBL.nt2[c1] + (rk2>>2);
      int slot = ((rk1&3)<<2) | (rk2&3);
      ((int*)(ws + WS_TMAP))[tl*16 + slot] = k;
    }
  }
}

// ============ K2: one TILE per block: reduce + gemm partials ==========
// grid NP2(824) x 256 -> ~3.2 blocks/CU (double R10's parallelism).
// Thread pair (b,sl): each half sums 8 of the 16 s-groups (loads hoisted
// before the tile decode), combined with one shfl_xor. GEMM chain is 8 deep.
__global__ __launch_bounds__(256) void k_p2(const float* __restrict__ wgt, char* ws)
{
  __shared__ float prob[NB*SLOTS_P2];   // 128 floats
  __shared__ int   krow[SLOTS_P2];      // 16
  __shared__ float hacc[2*NB*OUTS];     // 2048 floats (8 KB)
  int tid = threadIdx.x;
  int blk = blockIdx.x;                 // == tile index
  int slot0 = blk * SLOTS_P2;

  // ---- hoisted part loads: pair p = tid>>1 -> (b, sl); gh = tid&1 ----
  const float2* __restrict__ part = (const float2*)(ws + WS_PART);
  int pidx = tid >> 1, gh = tid & 1;
  int bb_ = pidx >> 4, sl_ = pidx & 15;
  float2 vv[8];
  #pragma unroll
  for (int g=0; g<8; g++)
    vv[g] = part[(size_t)(bb_*NSG + gh*8 + g)*NSLOTS + slot0 + sl_];

  // ---- tile decode (shared by all 16 slots; overlaps in-flight loads) ----
  if (tid < SLOTS_P2){
    int c = 0;
    while (blk >= TBL.tile_off[c+1]) c++;
    int local = blk - TBL.tile_off[c];
    int n2 = TBL.nt2[c];
    int ti = local / n2, tj = local - ti*n2;
    int r1 = ti*4 + (tid >> 2);
    int r2 = tj*4 + (tid & 3);
    bool pad = (r1 >= TBL.binom[8][c]) || (r2 >= TBL.binom[8][8-c]);
    krow[tid] = pad ? -1 : ((const int*)(ws + WS_TMAP))[slot0 + tid];
  }
  __syncthreads();

  // ---- reduce: half-sum + cross-lane combine ----
  {
    float2 amp = make_float2(0,0);
    #pragma unroll
    for (int g=0; g<8; g++){ amp.x += vv[g].x; amp.y += vv[g].y; }
    amp.x += __shfl_xor(amp.x, 1);
    amp.y += __shfl_xor(amp.y, 1);
    float pr = (krow[sl_] >= 0) ? fmaf(amp.x, amp.x, amp.y*amp.y) : 0.0f;
    if (gh == 0) prob[pidx] = pr;       // prob[b*16 + sl]
  }
  __syncthreads();

  // ---- norm partials: threads 0..127 hold prob[tid] ----
  float* __restrict__ bsum2 = (float*)(ws + WS_BSUM2);
  if (tid < 128){
    float v = prob[tid];
    #pragma unroll
    for (int off=8; off>0; off>>=1) v += __shfl_down(v, off, 16);
    if ((tid & 15) == 0) bsum2[blk*NB + (tid >> 4)] = v;
  }

  // ---- gemm: half h owns 8 slots, thread owns column o ----
  {
    int h = tid >> 7, o = tid & 127;
    float acc[NB] = {0,0,0,0,0,0,0,0};
    int sbeg = h*8, send = sbeg + 8;
    #pragma unroll
    for (int sl = sbeg; sl < send; sl++){
      int kr = krow[sl]; if (kr < 0) kr = 0;   // prob already 0 for pads
      float wv = wgt[(size_t)kr * OUTS + o];
      #pragma unroll
      for (int b=0;b<NB;b++) acc[b] = fmaf(prob[b*SLOTS_P2 + sl], wv, acc[b]);
    }
    #pragma unroll
    for (int b=0;b<NB;b++) hacc[h*(NB*OUTS) + b*OUTS + o] = acc[b];
  }
  __syncthreads();

  float* __restrict__ pout2 = (float*)(ws + WS_POUT2);
  for (int idx = tid; idx < NB*OUTS; idx += 256)
    pout2[(size_t)blk*(NB*OUTS) + idx] = hacc[idx] + hacc[NB*OUTS + idx];
}

// ============ K3: final reduce, 1024 threads, 8-way s-split ==========
// grid NB x 1024; 103 strided loads per group thread.
__global__ __launch_bounds__(1024) void k_p3(
    const float* __restrict__ bias, const char* __restrict__ ws,
    float* __restrict__ out)
{
  __shared__ float accs[8][OUTS];   // 4 KB
  __shared__ float wred[16];
  int tid = threadIdx.x, b = blockIdx.x;
  const float* __restrict__ bsum2 = (const float*)(ws + WS_BSUM2);
  const float* __restrict__ pout2 = (const float*)(ws + WS_POUT2);

  // norm: 1024-thread strided sum of NP2 entries (<=1 load each)
  float v = 0.0f;
  for (int j = tid; j < NP2; j += 1024) v += bsum2[j*NB + b];
  #pragma unroll
  for (int off=32; off>0; off>>=1) v += __shfl_down(v, off);
  if ((tid & 63) == 0) wred[tid >> 6] = v;

  // pout: group grp (0..7) sums s = grp, grp+8, ... (103 loads)
  int o = tid & 127, grp = tid >> 7;
  float a = 0.0f;
  for (int s = grp; s < NP2; s += 8) a += pout2[(size_t)s*(NB*OUTS) + b*OUTS + o];
  accs[grp][o] = a;
  __syncthreads();
  if (tid < OUTS){
    float norm = 0.0f;
    #pragma unroll
    for (int w=0; w<16; w++) norm += wred[w];
    float r = 0.0f;
    #pragma unroll
    for (int g=0; g<8; g++) r += accs[g][tid];
    out[b*OUTS + tid] = r / norm + bias[tid];
  }
}

// ---------------- launch ----------------
extern "C" void kernel_launch(void* const* d_in, const int* in_sizes, int n_in,
                              void* d_out, int out_size, void* d_ws, size_t ws_size,
                              hipStream_t stream) {
  const float* x    = (const float*)d_in[0];
  const float* th1  = (const float*)d_in[1];
  const float* th2  = (const float*)d_in[2];
  const float* mr   = (const float*)d_in[3];
  const float* mi   = (const float*)d_in[4];
  const float* wgt  = (const float*)d_in[5];
  const float* bias = (const float*)d_in[6];
  const int*   rows = (const int*)d_in[7];
  float* out = (float*)d_out;
  char* ws = (char*)d_ws;

  k_p1<<<NGRID, 256, 0, stream>>>(x, th1, th2, mr, mi, rows, ws);
  k_p2<<<NP2, 256, 0, stream>>>(wgt, ws);
  k_p3<<<NB, 1024, 0, stream>>>(bias, ws, out);
}

// Round 12
// 107.057 us; speedup vs baseline: 1.2494x; 1.2494x over previous
//
#include <hip/hip_runtime.h>
#include <math.h>

// ---------------- problem constants ----------------
#define NB 8          // batch
#define NM 16         // modes
#define NPH 8         // photons
#define NSTATES 12870 // C(16,8)
#define NSUB 256      // 2^NPH column subsets
#define OUTS 128
#define NTILES 824    // sum over classes of ceil(R/4)*ceil(C/4)
#define NSLOTS (NTILES*16) // 13184
#define NSG 16        // s-groups of 16
#define SPH 16        // s per producer block
#define NTG 4         // tile groups
#define TILES_PER_TG 206
#define NGRID 512     // NB * NSG * NTG
#define SLOTS_P2 32
#define NP2 412       // 412*32 == NSLOTS

// ---------------- compile-time tables ----------------
struct Tables {
  int binom[17][9];
  unsigned char cls_masks[256];
  int cls_off[10];
  int nt1[9], nt2[9];
  int tile_off[10];
};

constexpr int cpopc(int x){ int c=0; while(x){ c += x & 1; x >>= 1; } return c; }

constexpr Tables make_tables(){
  Tables t{};
  for (int n=0;n<=16;n++)
    for (int k=0;k<=8;k++){
      if (k==0) t.binom[n][k]=1;
      else if (n==0) t.binom[n][k]=0;
      else t.binom[n][k]=t.binom[n-1][k-1]+t.binom[n-1][k];
    }
  int idx=0;
  for (int p=0;p<=8;p++){
    t.cls_off[p]=idx;
    for (int m=0;m<256;m++) if (cpopc(m)==p) t.cls_masks[idx++]=(unsigned char)m;
  }
  t.cls_off[9]=idx; // 256
  int toff=0;
  for (int c=0;c<=8;c++){
    int R=t.binom[8][c], C=t.binom[8][8-c];
    t.nt1[c]=(R+3)/4; t.nt2[c]=(C+3)/4;
    t.tile_off[c]=toff; toff += t.nt1[c]*t.nt2[c];
  }
  t.tile_off[9]=toff;
  return t;
}

constexpr Tables HTBL = make_tables();
static_assert(HTBL.tile_off[9]==NTILES, "tile count");
static_assert(HTBL.cls_off[9]==256, "mask count");
__device__ const Tables TBL = HTBL;

// ---------------- workspace layout (bytes) ----------------
#define WS_TMAP   256               // NSLOTS ints = 52736 -> 52992 (pads never read)
#define WS_BSUM2  53248             // [NP2][NB] float = 13184 -> 66432
#define WS_POUT2  66560             // [NP2][NB*OUTS] float = 1687552 -> 1754112
#define WS_PART   1757184           // [NB][NSG][NSLOTS] float2 = 13500416

// ---------------- complex helpers ----------------
__device__ __forceinline__ float2 cmul(float2 a, float2 b){
  return make_float2(fmaf(a.x,b.x,-(a.y*b.y)), fmaf(a.x,b.y, a.y*b.x));
}
__device__ __forceinline__ void cmac(float2& acc, float2 a, float2 b){
  acc.x = fmaf(a.x, b.x, acc.x); acc.x = fmaf(-a.y, b.y, acc.x);
  acc.y = fmaf(a.x, b.y, acc.y); acc.y = fmaf(a.y, b.x, acc.y);
}

// ============ K1: fused setup + barrier-light Ryser main (R8/R10-verified) ==
// grid 512 = NB(8) x NSG(16) x NTG(4); 64 KB LDS, 256 thr -> 2 blocks/CU.
__global__ __launch_bounds__(256) void k_p1(
    const float* __restrict__ x, const float* __restrict__ th1,
    const float* __restrict__ th2, const float* __restrict__ mr,
    const float* __restrict__ mi, const int* __restrict__ rows, char* ws)
{
  __shared__ float2 P[32][256];      // 64 KB; row ts = table*16+s, col swizzled
  float2* __restrict__ part = (float2*)(ws + WS_PART);
  int tid = threadIdx.x;
  int blk = blockIdx.x;
  int b = blk >> 6, rest = blk & 63, sg = rest >> 2, tg = rest & 3;
  int sbase = sg * SPH;

  // prologue scratch aliased over P (dead before fill)
  float2 (*T1)[NM]  = reinterpret_cast<float2(*)[NM]>(P[0]);
  float2 (*T2)[NM]  = reinterpret_cast<float2(*)[NM]>(P[1]);
  float2 (*Am)[NM]  = reinterpret_cast<float2(*)[NM]>(P[2]);
  float2 (*Bm)[NM]  = reinterpret_cast<float2(*)[NM]>(P[3]);
  float2 (*EA)[NPH] = reinterpret_cast<float2(*)[NPH]>(P[4]);
  float2* exP = P[4] + 128;
  float2 (*UinL)[NPH] = reinterpret_cast<float2(*)[NPH]>(P[5]);

  {
    int r = tid >> 4, cc = tid & 15;
    float sn, cs;
    sincosf(th1[r], &sn, &cs);
    float a = mr[0*256 + tid], bb = mi[0*256 + tid];
    T1[r][cc] = make_float2(cs*a - sn*bb, cs*bb + sn*a);
    sincosf(th2[r], &sn, &cs);
    float a2 = mr[2*256 + tid], b2 = mi[2*256 + tid];
    T2[r][cc] = make_float2(cs*a2 - sn*b2, cs*b2 + sn*a2);
    if (tid < NM){ float s2, c2; sincosf(x[b*NM + tid], &s2, &c2); exP[tid] = make_float2(c2, s2); }
  }
  __syncthreads();
  {
    int r = tid >> 4, cc = tid & 15;
    float2 accA = make_float2(0,0), accB = make_float2(0,0);
    for (int m=0;m<NM;m++){
      float2 m1 = make_float2(mr[1*256 + r*16+m], mi[1*256 + r*16+m]);
      cmac(accA, m1, T1[m][cc]);
      float2 m3 = make_float2(mr[3*256 + r*16+m], mi[3*256 + r*16+m]);
      cmac(accB, m3, T2[m][cc]);
    }
    Am[r][cc] = accA; Bm[r][cc] = accB;
  }
  __syncthreads();
  if (tid < NM*NPH){ int m = tid >> 3, n = tid & 7; EA[m][n] = cmul(exP[m], Am[m][n]); }
  __syncthreads();
  if (tid < NM*NPH){
    int p = tid >> 3, n = tid & 7;
    float2 acc = make_float2(0,0);
    for (int m=0;m<NM;m++) cmac(acc, Bm[p][m], EA[m][n]);
    UinL[p][n] = acc;
  }
  __syncthreads();

  // per-thread V extraction into registers (same sum order as original)
  int ts = tid >> 3;
  int table = ts >> 4, sl = ts & 15;
  int sv = sbase + sl;
  float2 v[8];
  {
    #pragma unroll
    for (int j=0;j<8;j++){
      float2 a = make_float2(0,0);
      int m = table*8 + j;
      #pragma unroll
      for (int jj=0;jj<NPH;jj++)
        if ((sv>>jj) & 1){ a.x += UinL[m][jj].x; a.y += UinL[m][jj].y; }
      v[j] = a;
    }
  }
  __syncthreads();   // prologue scratch dead

  // fill: register DP in two 16-value halves (bit-identical multiply tree)
  {
    int chunk = tid & 7;
    int t0 = chunk << 5;
    int swz = (ts & 15) << 1;
    float2 ph = make_float2((table==0 && (__popc(sv)&1)) ? -1.0f : 1.0f, 0.0f);
    if (chunk & 4) ph = cmul(ph, v[7]);
    if (chunk & 2) ph = cmul(ph, v[6]);
    if (chunk & 1) ph = cmul(ph, v[5]);

    float2 pl[16];
    // half A: u = 0..15, root ph
    pl[0] = ph;
    #pragma unroll
    for (int w=1; w<16; w++){
      int par = w & (w-1);
      int lb = (w&1) ? 0 : ((w&2) ? 1 : ((w&4) ? 2 : 3));
      pl[w] = cmul(pl[par], v[lb]);
    }
    #pragma unroll
    for (int w=0; w<16; w+=2){
      int tc = (t0 + w) ^ swz;
      *(float4*)&P[ts][tc] = make_float4(pl[w].x, pl[w].y, pl[w+1].x, pl[w+1].y);
    }
    // half B: u = 16..31, root ph*v[4]  (== original p[16])
    pl[0] = cmul(ph, v[4]);
    #pragma unroll
    for (int w=1; w<16; w++){
      int par = w & (w-1);
      int lb = (w&1) ? 0 : ((w&2) ? 1 : ((w&4) ? 2 : 3));
      pl[w] = cmul(pl[par], v[lb]);
    }
    #pragma unroll
    for (int w=0; w<16; w+=2){
      int tc = (t0 + 16 + w) ^ swz;
      *(float4*)&P[ts][tc] = make_float4(pl[w].x, pl[w].y, pl[w+1].x, pl[w+1].y);
    }
  }

  // combine-thread tile masks
  bool active = tid < TILES_PER_TG;
  int tile = tg + 4*tid;
  int t1v[4] = {0,0,0,0}, t2v[4] = {0,0,0,0};
  if (active){
    int c = 0;
    while (tile >= TBL.tile_off[c+1]) c++;
    int local = tile - TBL.tile_off[c];
    int n2 = TBL.nt2[c];
    int ti = local / n2, tj = local - ti*n2;
    int R = TBL.binom[8][c], C2 = TBL.binom[8][8-c];
    #pragma unroll
    for (int i=0;i<4;i++){ int r1 = ti*4+i; t1v[i] = (r1<R) ? (int)TBL.cls_masks[TBL.cls_off[c]+r1] : 0; }
    #pragma unroll
    for (int j=0;j<4;j++){ int r2 = tj*4+j; t2v[j] = (r2<C2) ? (int)TBL.cls_masks[TBL.cls_off[8-c]+r2] : 0; }
  }
  __syncthreads();   // P table ready

  if (active){
    float2 acc[4][4] = {};
    for (int s=0;s<SPH;s++){
      int swz = s << 1;
      float2 av[4], bv[4];
      #pragma unroll
      for (int i=0;i<4;i++) av[i] = P[s][t1v[i] ^ swz];
      #pragma unroll
      for (int j=0;j<4;j++) bv[j] = P[16+s][t2v[j] ^ swz];
      #pragma unroll
      for (int i=0;i<4;i++)
        #pragma unroll
        for (int j=0;j<4;j++) cmac(acc[i][j], av[i], bv[j]);
    }
    float2* dst = part + (size_t)(b*NSG + sg)*NSLOTS + (size_t)tile*16;
    #pragma unroll
    for (int i=0;i<4;i++)
      #pragma unroll
      for (int j=0;j<4;j++) dst[i*4+j] = acc[i][j];
  }

  // tile map: tg==3 blocks rank 101 states each
  if (tg == 3){
    int idx = blk >> 2;
    int kb = idx * 101;
    int ke = min(NSTATES, kb + 101);
    int k = kb + tid;
    if (k < ke){
      int t1=0, t2=0;
      #pragma unroll
      for (int i=0;i<NPH;i++){
        int rr = rows[k*NPH+i];
        if (rr < 8) t1 |= 1 << rr; else t2 |= 1 << (rr-8);
      }
      int c1 = __popc(t1);
      int rk1=0, cnt=0;
      #pragma unroll
      for (int bb=0;bb<8;bb++) if ((t1>>bb)&1){ cnt++; rk1 += TBL.binom[bb][cnt]; }
      int rk2=0; cnt=0;
      #pragma unroll
      for (int bb=0;bb<8;bb++) if ((t2>>bb)&1){ cnt++; rk2 += TBL.binom[bb][cnt]; }
      int tl = TBL.tile_off[c1] + (rk1>>2)*TBL.nt2[c1] + (rk2>>2);
      int slot = ((rk1&3)<<2) | (rk2&3);
      ((int*)(ws + WS_TMAP))[tl*16 + slot] = k;
    }
  }
}

// ============ K2: slot-driven reduce + gemm partials (R10 structure) =======
// grid NP2(412) x 256. Block owns 32 consecutive slots. Part loads hoisted
// before the krow compute + barrier. GEMM loop now FULLY unrolled: all 16
// scattered weight-row loads per thread issue concurrently (they depend only
// on LDS-resident krow), 4x the in-flight MLP of the unroll-4 version.
__global__ __launch_bounds__(256) void k_p2(const float* __restrict__ wgt, char* ws)
{
  __shared__ float prob[NB*SLOTS_P2];   // 256 floats
  __shared__ int   krow[SLOTS_P2];
  __shared__ float hacc[2*NB*OUTS];     // 2048 floats (8 KB)
  int tid = threadIdx.x;
  int blk = blockIdx.x;
  int slot0 = blk * SLOTS_P2;

  // ---- issue the 16 part loads FIRST (independent of krow) ----
  const float2* __restrict__ part = (const float2*)(ws + WS_PART);
  int bb_ = tid >> 5, sl_ = tid & 31;
  float2 vv[NSG];
  #pragma unroll
  for (int g=0; g<NSG; g++)
    vv[g] = part[(size_t)(bb_*NSG + g)*NSLOTS + slot0 + sl_];

  // ---- krow (overlaps with the in-flight loads) ----
  if (tid < SLOTS_P2){
    int slot = slot0 + tid;
    int tile = slot >> 4;
    int c = 0;
    while (tile >= TBL.tile_off[c+1]) c++;
    int local = tile - TBL.tile_off[c];
    int n2 = TBL.nt2[c];
    int ti = local / n2, tj = local - ti*n2;
    int r1 = ti*4 + ((slot >> 2) & 3);
    int r2 = tj*4 + (slot & 3);
    bool pad = (r1 >= TBL.binom[8][c]) || (r2 >= TBL.binom[8][8-c]);
    krow[tid] = pad ? -1 : ((const int*)(ws + WS_TMAP))[slot];
  }
  __syncthreads();

  // ---- reduce (same summation order as before) + norm partial ----
  float* __restrict__ bsum2 = (float*)(ws + WS_BSUM2);
  {
    float2 amp = make_float2(0,0);
    #pragma unroll
    for (int g=0; g<NSG; g++){ amp.x += vv[g].x; amp.y += vv[g].y; }
    float pr = (krow[sl_] >= 0) ? fmaf(amp.x, amp.x, amp.y*amp.y) : 0.0f;
    prob[bb_*SLOTS_P2 + sl_] = pr;
    float v = pr;
    #pragma unroll
    for (int off=16; off>0; off>>=1) v += __shfl_down(v, off, 32);
    if (sl_ == 0) bsum2[blk*NB + bb_] = v;
  }
  __syncthreads();

  // ---- gemm: half h owns 16 slots, thread owns column o; FULL unroll ----
  {
    int h = tid >> 7, o = tid & 127;
    float acc[NB] = {0,0,0,0,0,0,0,0};
    int sbeg = h*16;
    #pragma unroll 16
    for (int u = 0; u < 16; u++){
      int sl = sbeg + u;
      int kr = krow[sl]; if (kr < 0) kr = 0;   // prob already 0 for pads
      float wv = wgt[(size_t)kr * OUTS + o];
      #pragma unroll
      for (int b=0;b<NB;b++) acc[b] = fmaf(prob[b*SLOTS_P2 + sl], wv, acc[b]);
    }
    #pragma unroll
    for (int b=0;b<NB;b++) hacc[h*(NB*OUTS) + b*OUTS + o] = acc[b];
  }
  __syncthreads();

  float* __restrict__ pout2 = (float*)(ws + WS_POUT2);
  for (int idx = tid; idx < NB*OUTS; idx += 256)
    pout2[(size_t)blk*(NB*OUTS) + idx] = hacc[idx] + hacc[NB*OUTS + idx];
}

// ============ K3: final reduce, 1024 threads, 8-way s-split ==========
// grid NB x 1024. The 52-deep pout sum now uses 4 independent accumulators:
// 4x in-flight loads + broken serial FMA chain.
__global__ __launch_bounds__(1024) void k_p3(
    const float* __restrict__ bias, const char* __restrict__ ws,
    float* __restrict__ out)
{
  __shared__ float accs[8][OUTS];   // 4 KB
  __shared__ float wred[16];
  int tid = threadIdx.x, b = blockIdx.x;
  const float* __restrict__ bsum2 = (const float*)(ws + WS_BSUM2);
  const float* __restrict__ pout2 = (const float*)(ws + WS_POUT2);

  // norm: 1024-thread strided sum of NP2 entries (<=1 load each)
  float v = 0.0f;
  for (int j = tid; j < NP2; j += 1024) v += bsum2[j*NB + b];
  #pragma unroll
  for (int off=32; off>0; off>>=1) v += __shfl_down(v, off);
  if ((tid & 63) == 0) wred[tid >> 6] = v;

  // pout: group grp (0..7) sums s = grp, grp+8, ...; 4 accumulators
  int o = tid & 127, grp = tid >> 7;
  const float* __restrict__ pb = pout2 + (size_t)b*OUTS + o;
  float a0 = 0.f, a1 = 0.f, a2 = 0.f, a3 = 0.f;
  int s = grp;
  for (; s + 24 < NP2; s += 32){
    a0 += pb[(size_t)(s     )*(NB*OUTS)];
    a1 += pb[(size_t)(s +  8)*(NB*OUTS)];
    a2 += pb[(size_t)(s + 16)*(NB*OUTS)];
    a3 += pb[(size_t)(s + 24)*(NB*OUTS)];
  }
  for (; s < NP2; s += 8) a0 += pb[(size_t)s*(NB*OUTS)];
  accs[grp][o] = (a0 + a1) + (a2 + a3);
  __syncthreads();
  if (tid < OUTS){
    float norm = 0.0f;
    #pragma unroll
    for (int w=0; w<16; w++) norm += wred[w];
    float r = 0.0f;
    #pragma unroll
    for (int g=0; g<8; g++) r += accs[g][tid];
    out[b*OUTS + tid] = r / norm + bias[tid];
  }
}

// ---------------- launch ----------------
extern "C" void kernel_launch(void* const* d_in, const int* in_sizes, int n_in,
                              void* d_out, int out_size, void* d_ws, size_t ws_size,
                              hipStream_t stream) {
  const float* x    = (const float*)d_in[0];
  const float* th1  = (const float*)d_in[1];
  const float* th2  = (const float*)d_in[2];
  const float* mr   = (const float*)d_in[3];
  const float* mi   = (const float*)d_in[4];
  const float* wgt  = (const float*)d_in[5];
  const float* bias = (const float*)d_in[6];
  const int*   rows = (const int*)d_in[7];
  float* out = (float*)d_out;
  char* ws = (char*)d_ws;

  k_p1<<<NGRID, 256, 0, stream>>>(x, th1, th2, mr, mi, rows, ws);
  k_p2<<<NP2, 256, 0, stream>>>(wgt, ws);
  k_p3<<<NB, 1024, 0, stream>>>(bias, ws, out);
}